// Round 3
// baseline (681.836 us; speedup 1.0000x reference)
//
#include <hip/hip_runtime.h>
#include <cstdint>
#include <cstddef>

#define BB 4
#define CC 2048
#define HH 48
#define WW 48
#define NN 2304       // HH*WW
#define CAMS 384

typedef unsigned short ushort_t;
typedef short bf16x8 __attribute__((ext_vector_type(8)));
typedef float f32x4 __attribute__((ext_vector_type(4)));

// ---- bf16 helpers (manual RNE) ----
__device__ __forceinline__ ushort_t f2bf(float f) {
    uint32_t u = __builtin_bit_cast(uint32_t, f);
    u += 0x7FFFu + ((u >> 16) & 1u);
    return (ushort_t)(u >> 16);
}
__device__ __forceinline__ float bf2f(ushort_t u) {
    return __builtin_bit_cast(float, (uint32_t)u << 16);
}

__device__ __forceinline__ void gld16(const void* g, void* l) {
    __builtin_amdgcn_global_load_lds(
        (const __attribute__((address_space(1))) uint32_t*)g,
        (__attribute__((address_space(3))) uint32_t*)l, 16, 0, 0);
}

// ---- BK=64 MFMA mainloop: D[m0..+128][n0..+128] += A[m][k]*B[n][k]
// A: [M][K] bf16 k-fast, B: [N][K] bf16 k-fast, K % 64 == 0.
// LDS rows are 128B (8 x 16B chunks); logical chunk c stored at physical
// c ^ (row&7) so both staging writes and b128 fragment reads stay balanced
// (each bank touched exactly 8x per wave instruction = b128 floor).
// 32 MFMAs between barrier pairs (2x m97 density). ----
__device__ __forceinline__ void mfma_mainloop(
    const ushort_t* __restrict__ A, const ushort_t* __restrict__ B, int K,
    int m0, int n0, ushort_t* sA, ushort_t* sB, f32x4 acc[4][4])
{
    const int t = threadIdx.x;
    const int lane = t & 63;
    const int w = t >> 6;
    const int wm = (w >> 1) * 64;
    const int wn = (w & 1) * 64;
    const int col = lane & 15;
    const int quad = lane >> 4;
    const int lr = lane >> 3;       // row within 8-row staging group
    const int lp = lane & 7;        // physical 16B chunk within 128B row

    for (int k0 = 0; k0 < K; k0 += 64) {
        __syncthreads();
        #pragma unroll
        for (int iss = 0; iss < 4; iss++) {
            const int rg = w * 32 + iss * 8;          // wave-uniform row base
            const int r = rg + lr;                    // tile-local row
            const int g = lp ^ (r & 7);               // logical chunk to fetch
            gld16(A + (size_t)(m0 + r) * K + k0 + g * 8, sA + rg * 64);
            gld16(B + (size_t)(n0 + r) * K + k0 + g * 8, sB + rg * 64);
        }
        __syncthreads();
        #pragma unroll
        for (int s = 0; s < 2; s++) {
            bf16x8 af[4], bfr[4];
            #pragma unroll
            for (int i = 0; i < 4; i++) {
                const int m = wm + i * 16 + col;
                af[i] = *(const bf16x8*)(sA + m * 64 + (((quad + 4 * s)) ^ (m & 7)) * 8);
            }
            #pragma unroll
            for (int j = 0; j < 4; j++) {
                const int n = wn + j * 16 + col;
                bfr[j] = *(const bf16x8*)(sB + n * 64 + (((quad + 4 * s)) ^ (n & 7)) * 8);
            }
            #pragma unroll
            for (int i = 0; i < 4; i++)
                #pragma unroll
                for (int j = 0; j < 4; j++)
                    acc[i][j] = __builtin_amdgcn_mfma_f32_16x16x32_bf16(
                        af[i], bfr[j], acc[i][j], 0, 0, 0);
        }
    }
}

// ---------------- init: zero norm + loss accumulators ----------------
__global__ void init_kernel(float* __restrict__ qn2, float* __restrict__ kn2,
                            float* __restrict__ accf) {
    int t = blockIdx.x * 256 + threadIdx.x;
    if (t < BB * NN) { qn2[t] = 0.f; kn2[t] = 0.f; }
    if (t == 0) { ((double*)accf)[0] = 0.0; ((unsigned int*)accf)[2] = 0u; }
}

// ---------------- W fp32 -> bf16 (layout unchanged, c fast) ----------------
__global__ void conv_w(const float* __restrict__ Wq, const float* __restrict__ Wk,
                       ushort_t* __restrict__ Wqb, ushort_t* __restrict__ Wkb) {
    const int per = CC * CC / 4;
    int idx = blockIdx.x * 256 + threadIdx.x;
    if (idx >= 2 * per) return;
    const float4* src; ushort_t* dst; int i;
    if (idx < per) { src = (const float4*)Wq; dst = Wqb; i = idx; }
    else           { src = (const float4*)Wk; dst = Wkb; i = idx - per; }
    float4 v = src[i];
    ushort_t* o = dst + (size_t)i * 4;
    o[0] = f2bf(v.x); o[1] = f2bf(v.y); o[2] = f2bf(v.z); o[3] = f2bf(v.w);
}

// ---------------- x fp32 [b][c][n] -> xbf bf16 same + xT bf16 [b][n][c] ----
__global__ void conv_x(const float* __restrict__ x, ushort_t* __restrict__ xbf,
                       ushort_t* __restrict__ xT) {
    __shared__ float tile[32][33];
    const int b = blockIdx.z;
    const int c0 = blockIdx.y * 32, n0 = blockIdx.x * 32;
    const int tx = threadIdx.x, ty = threadIdx.y;   // 32 x 8
    #pragma unroll
    for (int r = 0; r < 32; r += 8) {
        size_t gi = ((size_t)b * CC + c0 + ty + r) * NN + n0 + tx;
        float v = x[gi];
        xbf[gi] = f2bf(v);
        tile[ty + r][tx] = v;
    }
    __syncthreads();
    #pragma unroll
    for (int r = 0; r < 32; r += 8) {
        xT[((size_t)b * NN + n0 + ty + r) * CC + c0 + tx] = f2bf(tile[tx][ty + r]);
    }
}

// ---------------- merged proj (q and k): outT[b][n][o] = sum_c xT[n][c]*W[o][c]+bias
// grid.z = b*2 + which; fused row-norm accumulation (sum_o val^2). ----
__global__ __launch_bounds__(256) void gemm_proj(
    const ushort_t* __restrict__ xT,
    const ushort_t* __restrict__ Wqb, const ushort_t* __restrict__ Wkb,
    const float* __restrict__ bq, const float* __restrict__ bk,
    ushort_t* __restrict__ qT, ushort_t* __restrict__ kT,
    float* __restrict__ qn2, float* __restrict__ kn2)
{
    __shared__ __align__(16) ushort_t sA[128 * 64];
    __shared__ __align__(16) ushort_t sB[128 * 64];
    const int z = blockIdx.z;
    const int b = z >> 1, which = z & 1;
    const ushort_t* Wb  = which ? Wkb : Wqb;
    const float*    bias = which ? bk  : bq;
    ushort_t*       outT = which ? kT  : qT;
    float*          nrm  = which ? kn2 : qn2;
    const int m0 = blockIdx.y * 128;   // n
    const int n0 = blockIdx.x * 128;   // o
    f32x4 acc[4][4];
    const f32x4 zz = {0.f, 0.f, 0.f, 0.f};
    #pragma unroll
    for (int i = 0; i < 4; i++)
        #pragma unroll
        for (int j = 0; j < 4; j++) acc[i][j] = zz;
    mfma_mainloop(xT + (size_t)b * NN * CC, Wb, CC, m0, n0, sA, sB, acc);
    const int t = threadIdx.x, lane = t & 63, w = t >> 6;
    const int wm = (w >> 1) * 64, wn = (w & 1) * 64;
    const int col = lane & 15, quad = lane >> 4;
    ushort_t* O = outT + (size_t)b * NN * CC;
    float sq[4][4];
    #pragma unroll
    for (int i = 0; i < 4; i++)
        #pragma unroll
        for (int r = 0; r < 4; r++) sq[i][r] = 0.f;
    #pragma unroll
    for (int j = 0; j < 4; j++) {
        const int gn = n0 + wn + j * 16 + col;     // o
        const float bv = bias[gn];
        #pragma unroll
        for (int i = 0; i < 4; i++) {
            const int gm = m0 + wm + i * 16 + quad * 4;   // n
            #pragma unroll
            for (int r = 0; r < 4; r++) {
                ushort_t hb = f2bf(acc[i][j][r] + bv);
                O[(size_t)(gm + r) * CC + gn] = hb;
                float vq = bf2f(hb);
                sq[i][r] += vq * vq;
            }
        }
    }
    // reduce sum-of-squares across the 16 col-lanes of each quad
    #pragma unroll
    for (int i = 0; i < 4; i++)
        #pragma unroll
        for (int r = 0; r < 4; r++) {
            float s = sq[i][r];
            #pragma unroll
            for (int o = 1; o < 16; o <<= 1) s += __shfl_xor(s, o, 64);
            if (col == 0) {
                const int gm = m0 + wm + i * 16 + quad * 4 + r;
                atomicAdd(&nrm[b * NN + gm], s);
            }
        }
}

// ---------------- energy: S[b][n][m] = sum_o qT[n][o]*kT[m][o] (bf16) ----
__global__ __launch_bounds__(256) void gemm_energy(
    const ushort_t* __restrict__ qT, const ushort_t* __restrict__ kT,
    ushort_t* __restrict__ S)
{
    __shared__ __align__(16) ushort_t sA[128 * 64];
    __shared__ __align__(16) ushort_t sB[128 * 64];
    const int b = blockIdx.z;
    const int m0 = blockIdx.y * 128;   // n
    const int n0 = blockIdx.x * 128;   // m
    f32x4 acc[4][4];
    const f32x4 zz = {0.f, 0.f, 0.f, 0.f};
    #pragma unroll
    for (int i = 0; i < 4; i++)
        #pragma unroll
        for (int j = 0; j < 4; j++) acc[i][j] = zz;
    mfma_mainloop(qT + (size_t)b * NN * CC, kT + (size_t)b * NN * CC, CC,
                  m0, n0, sA, sB, acc);
    const int t = threadIdx.x, lane = t & 63, w = t >> 6;
    const int wm = (w >> 1) * 64, wn = (w & 1) * 64;
    const int col = lane & 15, quad = lane >> 4;
    ushort_t* O = S + (size_t)b * NN * NN;
    #pragma unroll
    for (int i = 0; i < 4; i++) {
        const int gm = m0 + wm + i * 16 + quad * 4;
        #pragma unroll
        for (int j = 0; j < 4; j++) {
            const int gn = n0 + wn + j * 16 + col;
            #pragma unroll
            for (int r = 0; r < 4; r++)
                O[(size_t)(gm + r) * NN + gn] = f2bf(acc[i][j][r]);
        }
    }
}

// ---------------- softmax row n over m, scale rsqrt(qn2*kn2), inline mask --
__global__ __launch_bounds__(256) void softmax_kernel(
    ushort_t* __restrict__ S, const float* __restrict__ qn2,
    const float* __restrict__ kn2, const float* __restrict__ cam)
{
    const int n = blockIdx.x, b = blockIdx.y;
    ushort_t* row = S + ((size_t)b * NN + n) * NN;
    const float qinv = rsqrtf(qn2[b * NN + n]);
    // inline bilinear mask for this query row
    const int y = n / WW, xx = n % WW;
    const float ys = (float)(y  * (CAMS - 1)) / (float)(HH - 1);
    const float xs = (float)(xx * (CAMS - 1)) / (float)(WW - 1);
    const int y0 = (int)ys, x0 = (int)xs;
    const int y1 = min(y0 + 1, CAMS - 1), x1 = min(x0 + 1, CAMS - 1);
    const float wy = ys - (float)y0, wx = xs - (float)x0;
    const float* cb = cam + (size_t)b * CAMS * CAMS;
    float c00 = cb[y0 * CAMS + x0]; if (c00 == 255.f) c00 = 0.f;
    float c01 = cb[y0 * CAMS + x1]; if (c01 == 255.f) c01 = 0.f;
    float c10 = cb[y1 * CAMS + x0]; if (c10 == 255.f) c10 = 0.f;
    float c11 = cb[y1 * CAMS + x1]; if (c11 == 255.f) c11 = 0.f;
    const float mv = (1.f - wy) * ((1.f - wx) * c00 + wx * c01)
                   +        wy  * ((1.f - wx) * c10 + wx * c11);
    const float mval = (mv > 0.f) ? 1.f : 0.f;

    const int t = threadIdx.x;
    float v[9];
    float vmax = -3.4e38f;
    #pragma unroll
    for (int i = 0; i < 9; i++) {
        int idx = t + i * 256;
        float s = bf2f(row[idx]) * qinv * rsqrtf(kn2[b * NN + idx]);
        v[i] = s;
        vmax = fmaxf(vmax, s);
    }
    __shared__ float red[8];
    int lane = t & 63, wid = t >> 6;
    #pragma unroll
    for (int o = 32; o; o >>= 1) vmax = fmaxf(vmax, __shfl_down(vmax, o, 64));
    if (!lane) red[wid] = vmax;
    __syncthreads();
    vmax = fmaxf(fmaxf(red[0], red[1]), fmaxf(red[2], red[3]));
    float s = 0.f;
    #pragma unroll
    for (int i = 0; i < 9; i++) { v[i] = __expf(v[i] - vmax); s += v[i]; }
    #pragma unroll
    for (int o = 32; o; o >>= 1) s += __shfl_down(s, o, 64);
    if (!lane) red[4 + wid] = s;
    __syncthreads();
    s = red[4] + red[5] + red[6] + red[7];
    const float scale = mval / s;
    #pragma unroll
    for (int i = 0; i < 9; i++) row[t + i * 256] = f2bf(v[i] * scale);
}

// ---------------- out: new_x[c][n] = sum_m xbf[c][m]*att[n][m]; fused loss -
__global__ __launch_bounds__(256) void gemm_out_loss(
    const ushort_t* __restrict__ xbf, const ushort_t* __restrict__ att,
    const float* __restrict__ x, const float* __restrict__ gamma,
    float* __restrict__ accf)
{
    __shared__ __align__(16) ushort_t sA[128 * 64];
    __shared__ __align__(16) ushort_t sB[128 * 64];
    const int b = blockIdx.z;
    const int m0 = blockIdx.y * 128;   // c
    const int n0 = blockIdx.x * 128;   // n
    f32x4 acc[4][4];
    const f32x4 zz = {0.f, 0.f, 0.f, 0.f};
    #pragma unroll
    for (int i = 0; i < 4; i++)
        #pragma unroll
        for (int j = 0; j < 4; j++) acc[i][j] = zz;
    mfma_mainloop(xbf + (size_t)b * CC * NN, att + (size_t)b * NN * NN, NN,
                  m0, n0, sA, sB, acc);
    const int t = threadIdx.x, lane = t & 63, w = t >> 6;
    const int wm = (w >> 1) * 64, wn = (w & 1) * 64;
    const int col = lane & 15, quad = lane >> 4;
    const float g = gamma[0];
    const float* Xb = x + (size_t)b * CC * NN;
    float lsum = 0.f;
    unsigned int lcnt = 0;
    #pragma unroll
    for (int i = 0; i < 4; i++) {
        const int gm = m0 + wm + i * 16 + quad * 4;   // c
        #pragma unroll
        for (int j = 0; j < 4; j++) {
            const int gn = n0 + wn + j * 16 + col;    // n
            #pragma unroll
            for (int r = 0; r < 4; r++) {
                float xv = Xb[(size_t)(gm + r) * NN + gn];
                float d = xv - g * acc[i][j][r];
                float r2 = d * d;
                lsum += r2;
                lcnt += (r2 != 0.f) ? 1u : 0u;
            }
        }
    }
    #pragma unroll
    for (int o = 32; o; o >>= 1) {
        lsum += __shfl_down(lsum, o, 64);
        lcnt += __shfl_down(lcnt, o, 64);
    }
    __shared__ float rs[4];
    __shared__ unsigned int rc[4];
    if (!lane) { rs[w] = lsum; rc[w] = lcnt; }
    __syncthreads();
    if (t == 0) {
        double tot = (double)rs[0] + rs[1] + rs[2] + rs[3];
        unsigned int ct = rc[0] + rc[1] + rc[2] + rc[3];
        atomicAdd((double*)accf, tot);
        atomicAdd(((unsigned int*)accf) + 2, ct);
    }
}

__global__ void finalize_kernel(const float* __restrict__ accf, float* __restrict__ out) {
    double s = ((const double*)accf)[0];
    unsigned int c = ((const unsigned int*)accf)[2];
    out[0] = (float)(s / (double)c);
}

extern "C" void kernel_launch(void* const* d_in, const int* in_sizes, int n_in,
                              void* d_out, int out_size, void* d_ws, size_t ws_size,
                              hipStream_t stream) {
    const float* x     = (const float*)d_in[0];
    const float* cam   = (const float*)d_in[1];
    const float* Wq    = (const float*)d_in[2];
    const float* bq    = (const float*)d_in[3];
    const float* Wk    = (const float*)d_in[4];
    const float* bk    = (const float*)d_in[5];
    const float* gamma = (const float*)d_in[6];

    uint8_t* ws = (uint8_t*)d_ws;
    size_t off = 0;
    auto alloc = [&](size_t bytes) {
        void* p = ws + off;
        off = (off + bytes + 255) & ~(size_t)255;
        return p;
    };
    ushort_t* qT   = (ushort_t*)alloc((size_t)BB * NN * CC * 2);
    ushort_t* kT   = (ushort_t*)alloc((size_t)BB * NN * CC * 2);
    ushort_t* S    = (ushort_t*)alloc((size_t)BB * NN * NN * 2);  // scores -> att
    ushort_t* xT   = (ushort_t*)alloc((size_t)BB * NN * CC * 2);
    ushort_t* xbf  = (ushort_t*)alloc((size_t)BB * CC * NN * 2);
    ushort_t* Wqb  = (ushort_t*)alloc((size_t)CC * CC * 2);
    ushort_t* Wkb  = (ushort_t*)alloc((size_t)CC * CC * 2);
    float*    qn2  = (float*)alloc((size_t)BB * NN * 4);
    float*    kn2  = (float*)alloc((size_t)BB * NN * 4);
    float*    acc  = (float*)alloc(16);

    hipLaunchKernelGGL(init_kernel, dim3((BB * NN + 255) / 256), dim3(256), 0, stream,
                       qn2, kn2, acc);
    hipLaunchKernelGGL(conv_w, dim3(2 * CC * CC / 4 / 256), dim3(256), 0, stream,
                       Wq, Wk, Wqb, Wkb);
    hipLaunchKernelGGL(conv_x, dim3(NN / 32, CC / 32, BB), dim3(32, 8), 0, stream,
                       x, xbf, xT);
    hipLaunchKernelGGL(gemm_proj, dim3(CC / 128, NN / 128, BB * 2), dim3(256), 0, stream,
                       xT, Wqb, Wkb, bq, bk, qT, kT, qn2, kn2);
    hipLaunchKernelGGL(gemm_energy, dim3(NN / 128, NN / 128, BB), dim3(256), 0, stream,
                       qT, kT, S);
    hipLaunchKernelGGL(softmax_kernel, dim3(NN, BB), dim3(256), 0, stream,
                       S, qn2, kn2, cam);
    hipLaunchKernelGGL(gemm_out_loss, dim3(NN / 128, CC / 128, BB), dim3(256), 0, stream,
                       xbf, S, x, gamma, acc);
    hipLaunchKernelGGL(finalize_kernel, dim3(1), dim3(1), 0, stream, acc, (float*)d_out);
}

// Round 4
// 651.031 us; speedup vs baseline: 1.0473x; 1.0473x over previous
//
#include <hip/hip_runtime.h>
#include <cstdint>
#include <cstddef>

#define BB 4
#define CC 2048
#define HH 48
#define WW 48
#define NN 2304       // HH*WW
#define CAMS 384

typedef unsigned short ushort_t;
typedef float f32x4 __attribute__((ext_vector_type(4)));

// ---- bf16 helpers ----
__device__ __forceinline__ ushort_t f2bf(float f) {
    uint32_t u = __builtin_bit_cast(uint32_t, f);
    u += 0x7FFFu + ((u >> 16) & 1u);
    return (ushort_t)(u >> 16);
}
__device__ __forceinline__ float bf2f(ushort_t u) {
    return __builtin_bit_cast(float, (uint32_t)u << 16);
}

// ---- fp8 e4m3 (OCP on gfx950) via HW cvt ----
__device__ __forceinline__ uint32_t pk2fp8(float a, float b) {
    // returns a|b<<8 in low 16 bits
    return (uint32_t)__builtin_amdgcn_cvt_pk_fp8_f32(a, b, 0, false) & 0xFFFFu;
}
__device__ __forceinline__ uint8_t f2fp8(float v) {
    return (uint8_t)(pk2fp8(v, v) & 0xFFu);
}

__device__ __forceinline__ void gld16(const void* g, void* l) {
    __builtin_amdgcn_global_load_lds(
        (const __attribute__((address_space(1))) uint32_t*)g,
        (__attribute__((address_space(3))) uint32_t*)l, 16, 0, 0);
}

// ---- fp8 MFMA mainloop: D[m0..+128][n0..+128] += A[m][k]*B[n][k]
// A: [M][K] fp8 k-fast (K bytes/row), B: [N][K] fp8 k-fast, K % 64 == 0.
// BK = 64 bytes -> LDS rows 64B (4 x 16B chunks), 8KB/buffer, 16KB total
// (round-2 occupancy). Logical chunk c of row r stored at physical c^(r&3).
// Per k0: 4 gld16/lane staging, then 2 x (8 ds_read_b64 + 8 MFMA). ----
__device__ __forceinline__ void mfma_mainloop_fp8(
    const uint8_t* __restrict__ A, const uint8_t* __restrict__ B, int K,
    int m0, int n0, uint8_t* sA, uint8_t* sB, f32x4 acc[4][4])
{
    const int t = threadIdx.x;
    const int lane = t & 63;
    const int w = t >> 6;
    const int wm = (w >> 1) * 64;
    const int wn = (w & 1) * 64;
    const int col = lane & 15;
    const int quad = lane >> 4;
    const int lr = lane >> 2;       // row within 16-row staging group
    const int lp = lane & 3;        // physical 16B chunk within 64B row

    for (int k0 = 0; k0 < K; k0 += 64) {
        __syncthreads();
        #pragma unroll
        for (int it = 0; it < 2; it++) {
            const int rg = w * 32 + it * 16;          // wave-uniform row base
            const int r = rg + lr;                    // tile-local row
            const int c = lp ^ (r & 3);               // logical chunk to fetch
            gld16(A + (size_t)(m0 + r) * K + k0 + c * 16, sA + rg * 64);
            gld16(B + (size_t)(n0 + r) * K + k0 + c * 16, sB + rg * 64);
        }
        __syncthreads();
        #pragma unroll
        for (int s = 0; s < 2; s++) {
            const int bo = s * 32 + quad * 8;         // byte offset of lane's k
            const int lc = bo >> 4;                   // logical chunk
            const int bi = bo & 15;                   // byte within chunk
            long af[4], bfr[4];
            #pragma unroll
            for (int i = 0; i < 4; i++) {
                const int m = wm + i * 16 + col;
                af[i] = *(const long*)(sA + m * 64 + (lc ^ (m & 3)) * 16 + bi);
            }
            #pragma unroll
            for (int j = 0; j < 4; j++) {
                const int n = wn + j * 16 + col;
                bfr[j] = *(const long*)(sB + n * 64 + (lc ^ (n & 3)) * 16 + bi);
            }
            #pragma unroll
            for (int i = 0; i < 4; i++)
                #pragma unroll
                for (int j = 0; j < 4; j++)
                    acc[i][j] = __builtin_amdgcn_mfma_f32_16x16x32_fp8_fp8(
                        af[i], bfr[j], acc[i][j], 0, 0, 0);
        }
    }
}

// ---------------- init: zero norm + loss accumulators ----------------
__global__ void init_kernel(float* __restrict__ qn2, float* __restrict__ kn2,
                            float* __restrict__ accf) {
    int t = blockIdx.x * 256 + threadIdx.x;
    if (t < BB * NN) { qn2[t] = 0.f; kn2[t] = 0.f; }
    if (t == 0) { ((double*)accf)[0] = 0.0; ((unsigned int*)accf)[2] = 0u; }
}

// ---------------- W fp32 -> fp8 (layout unchanged, c fast) ----------------
__global__ void conv_w(const float* __restrict__ Wq, const float* __restrict__ Wk,
                       uint8_t* __restrict__ Wq8, uint8_t* __restrict__ Wk8) {
    const int per = CC * CC / 4;
    int idx = blockIdx.x * 256 + threadIdx.x;
    if (idx >= 2 * per) return;
    const float4* src; uint8_t* dst; int i;
    if (idx < per) { src = (const float4*)Wq; dst = Wq8; i = idx; }
    else           { src = (const float4*)Wk; dst = Wk8; i = idx - per; }
    float4 v = src[i];
    *(uint32_t*)(dst + (size_t)i * 4) = pk2fp8(v.x, v.y) | (pk2fp8(v.z, v.w) << 16);
}

// ---------------- x fp32 [b][c][n] -> x8 fp8 same + xT8 fp8 [b][n][c] -----
__global__ void conv_x(const float* __restrict__ x, uint8_t* __restrict__ x8,
                       uint8_t* __restrict__ xT8) {
    __shared__ float tile[32][33];
    const int b = blockIdx.z;
    const int c0 = blockIdx.y * 32, n0 = blockIdx.x * 32;
    const int t = threadIdx.x;
    {
        const int c = t >> 3, n4 = (t & 7) * 4;
        const float4 v = *(const float4*)(x + ((size_t)b * CC + c0 + c) * NN + n0 + n4);
        *(uint32_t*)(x8 + ((size_t)b * CC + c0 + c) * NN + n0 + n4) =
            pk2fp8(v.x, v.y) | (pk2fp8(v.z, v.w) << 16);
        tile[c][n4] = v.x; tile[c][n4 + 1] = v.y;
        tile[c][n4 + 2] = v.z; tile[c][n4 + 3] = v.w;
    }
    __syncthreads();
    {
        const int n = t >> 3, c4 = (t & 7) * 4;
        uint32_t u = pk2fp8(tile[c4][n], tile[c4 + 1][n])
                   | (pk2fp8(tile[c4 + 2][n], tile[c4 + 3][n]) << 16);
        *(uint32_t*)(xT8 + ((size_t)b * NN + n0 + n) * CC + c0 + c4) = u;
    }
}

// ---------------- merged proj (q and k): outT[b][n][o] = sum_c xT[n][c]*W[o][c]+bias
// grid.z = b*2 + which; fused row-norm accumulation from fp32 accs. ----
__global__ __launch_bounds__(256) void gemm_proj(
    const uint8_t* __restrict__ xT8,
    const uint8_t* __restrict__ Wq8, const uint8_t* __restrict__ Wk8,
    const float* __restrict__ bq, const float* __restrict__ bk,
    uint8_t* __restrict__ qT8, uint8_t* __restrict__ kT8,
    float* __restrict__ qn2, float* __restrict__ kn2)
{
    __shared__ __align__(16) uint8_t sA[128 * 64];
    __shared__ __align__(16) uint8_t sB[128 * 64];
    const int z = blockIdx.z;
    const int b = z >> 1, which = z & 1;
    const uint8_t* Wb   = which ? Wk8 : Wq8;
    const float*   bias = which ? bk  : bq;
    uint8_t*       outT = which ? kT8 : qT8;
    float*         nrm  = which ? kn2 : qn2;
    const int m0 = blockIdx.y * 128;   // n
    const int n0 = blockIdx.x * 128;   // o
    f32x4 acc[4][4];
    const f32x4 zz = {0.f, 0.f, 0.f, 0.f};
    #pragma unroll
    for (int i = 0; i < 4; i++)
        #pragma unroll
        for (int j = 0; j < 4; j++) acc[i][j] = zz;
    mfma_mainloop_fp8(xT8 + (size_t)b * NN * CC, Wb, CC, m0, n0, sA, sB, acc);
    const int t = threadIdx.x, lane = t & 63, w = t >> 6;
    const int wm = (w >> 1) * 64, wn = (w & 1) * 64;
    const int col = lane & 15, quad = lane >> 4;
    uint8_t* O = outT + (size_t)b * NN * CC;
    float sq[4][4];
    #pragma unroll
    for (int i = 0; i < 4; i++)
        #pragma unroll
        for (int r = 0; r < 4; r++) sq[i][r] = 0.f;
    #pragma unroll
    for (int j = 0; j < 4; j++) {
        const int gn = n0 + wn + j * 16 + col;     // o
        const float bv = bias[gn];
        #pragma unroll
        for (int i = 0; i < 4; i++) {
            const int gm = m0 + wm + i * 16 + quad * 4;   // n
            #pragma unroll
            for (int r = 0; r < 4; r++) {
                float v = acc[i][j][r] + bv;
                O[(size_t)(gm + r) * CC + gn] = f2fp8(v);
                sq[i][r] += v * v;
            }
        }
    }
    #pragma unroll
    for (int i = 0; i < 4; i++)
        #pragma unroll
        for (int r = 0; r < 4; r++) {
            float s = sq[i][r];
            #pragma unroll
            for (int o = 1; o < 16; o <<= 1) s += __shfl_xor(s, o, 64);
            if (col == 0) {
                const int gm = m0 + wm + i * 16 + quad * 4 + r;
                atomicAdd(&nrm[b * NN + gm], s);
            }
        }
}

// ---------------- energy: S[b][n][m] = sum_o qT[n][o]*kT[m][o] (bf16 out) --
__global__ __launch_bounds__(256) void gemm_energy(
    const uint8_t* __restrict__ qT8, const uint8_t* __restrict__ kT8,
    ushort_t* __restrict__ S)
{
    __shared__ __align__(16) uint8_t sA[128 * 64];
    __shared__ __align__(16) uint8_t sB[128 * 64];
    const int b = blockIdx.z;
    const int m0 = blockIdx.y * 128;   // n
    const int n0 = blockIdx.x * 128;   // m
    f32x4 acc[4][4];
    const f32x4 zz = {0.f, 0.f, 0.f, 0.f};
    #pragma unroll
    for (int i = 0; i < 4; i++)
        #pragma unroll
        for (int j = 0; j < 4; j++) acc[i][j] = zz;
    mfma_mainloop_fp8(qT8 + (size_t)b * NN * CC, kT8 + (size_t)b * NN * CC, CC,
                      m0, n0, sA, sB, acc);
    const int t = threadIdx.x, lane = t & 63, w = t >> 6;
    const int wm = (w >> 1) * 64, wn = (w & 1) * 64;
    const int col = lane & 15, quad = lane >> 4;
    ushort_t* O = S + (size_t)b * NN * NN;
    #pragma unroll
    for (int i = 0; i < 4; i++) {
        const int gm = m0 + wm + i * 16 + quad * 4;
        #pragma unroll
        for (int j = 0; j < 4; j++) {
            const int gn = n0 + wn + j * 16 + col;
            #pragma unroll
            for (int r = 0; r < 4; r++)
                O[(size_t)(gm + r) * NN + gn] = f2bf(acc[i][j][r]);
        }
    }
}

// ---------------- softmax row n over m, scale rsqrt(qn2*kn2), inline mask,
// write att = mask*softmax*256 as fp8 (x256 escapes e4m3 subnormal floor) --
__global__ __launch_bounds__(256) void softmax_kernel(
    const ushort_t* __restrict__ S, uint8_t* __restrict__ att,
    const float* __restrict__ qn2, const float* __restrict__ kn2,
    const float* __restrict__ cam)
{
    const int n = blockIdx.x, b = blockIdx.y;
    const ushort_t* row = S + ((size_t)b * NN + n) * NN;
    uint8_t* orow = att + ((size_t)b * NN + n) * NN;
    const float qinv = rsqrtf(qn2[b * NN + n]);
    // inline bilinear mask for this query row
    const int y = n / WW, xx = n % WW;
    const float ys = (float)(y  * (CAMS - 1)) / (float)(HH - 1);
    const float xs = (float)(xx * (CAMS - 1)) / (float)(WW - 1);
    const int y0 = (int)ys, x0 = (int)xs;
    const int y1 = min(y0 + 1, CAMS - 1), x1 = min(x0 + 1, CAMS - 1);
    const float wy = ys - (float)y0, wx = xs - (float)x0;
    const float* cb = cam + (size_t)b * CAMS * CAMS;
    float c00 = cb[y0 * CAMS + x0]; if (c00 == 255.f) c00 = 0.f;
    float c01 = cb[y0 * CAMS + x1]; if (c01 == 255.f) c01 = 0.f;
    float c10 = cb[y1 * CAMS + x0]; if (c10 == 255.f) c10 = 0.f;
    float c11 = cb[y1 * CAMS + x1]; if (c11 == 255.f) c11 = 0.f;
    const float mv = (1.f - wy) * ((1.f - wx) * c00 + wx * c01)
                   +        wy  * ((1.f - wx) * c10 + wx * c11);
    const float mval = (mv > 0.f) ? 1.f : 0.f;

    const int t = threadIdx.x;
    float v[9];
    float vmax = -3.4e38f;
    #pragma unroll
    for (int i = 0; i < 9; i++) {
        int idx = t + i * 256;
        float s = bf2f(row[idx]) * qinv * rsqrtf(kn2[b * NN + idx]);
        v[i] = s;
        vmax = fmaxf(vmax, s);
    }
    __shared__ float red[8];
    int lane = t & 63, wid = t >> 6;
    #pragma unroll
    for (int o = 32; o; o >>= 1) vmax = fmaxf(vmax, __shfl_down(vmax, o, 64));
    if (!lane) red[wid] = vmax;
    __syncthreads();
    vmax = fmaxf(fmaxf(red[0], red[1]), fmaxf(red[2], red[3]));
    float s = 0.f;
    #pragma unroll
    for (int i = 0; i < 9; i++) { v[i] = __expf(v[i] - vmax); s += v[i]; }
    #pragma unroll
    for (int o = 32; o; o >>= 1) s += __shfl_down(s, o, 64);
    if (!lane) red[4 + wid] = s;
    __syncthreads();
    s = red[4] + red[5] + red[6] + red[7];
    const float scale = mval * 256.f / s;
    #pragma unroll
    for (int i = 0; i < 9; i++) orow[t + i * 256] = f2fp8(v[i] * scale);
}

// ---------------- out: new_x[c][n] = sum_m x8[c][m]*att[n][m]; fused loss --
__global__ __launch_bounds__(256) void gemm_out_loss(
    const uint8_t* __restrict__ x8, const uint8_t* __restrict__ att,
    const float* __restrict__ x, const float* __restrict__ gamma,
    float* __restrict__ accf)
{
    __shared__ __align__(16) uint8_t sA[128 * 64];
    __shared__ __align__(16) uint8_t sB[128 * 64];
    const int b = blockIdx.z;
    const int m0 = blockIdx.y * 128;   // c
    const int n0 = blockIdx.x * 128;   // n
    f32x4 acc[4][4];
    const f32x4 zz = {0.f, 0.f, 0.f, 0.f};
    #pragma unroll
    for (int i = 0; i < 4; i++)
        #pragma unroll
        for (int j = 0; j < 4; j++) acc[i][j] = zz;
    mfma_mainloop_fp8(x8 + (size_t)b * CC * NN, att + (size_t)b * NN * NN, NN,
                      m0, n0, sA, sB, acc);
    const int t = threadIdx.x, lane = t & 63, w = t >> 6;
    const int wm = (w >> 1) * 64, wn = (w & 1) * 64;
    const int col = lane & 15, quad = lane >> 4;
    const float g = gamma[0] * (1.f / 256.f);   // undo att x256 pre-scale
    const float* Xb = x + (size_t)b * CC * NN;
    float lsum = 0.f;
    unsigned int lcnt = 0;
    #pragma unroll
    for (int i = 0; i < 4; i++) {
        const int gm = m0 + wm + i * 16 + quad * 4;   // c
        #pragma unroll
        for (int j = 0; j < 4; j++) {
            const int gn = n0 + wn + j * 16 + col;    // n
            #pragma unroll
            for (int r = 0; r < 4; r++) {
                float xv = Xb[(size_t)(gm + r) * NN + gn];
                float d = xv - g * acc[i][j][r];
                float r2 = d * d;
                lsum += r2;
                lcnt += (r2 != 0.f) ? 1u : 0u;
            }
        }
    }
    #pragma unroll
    for (int o = 32; o; o >>= 1) {
        lsum += __shfl_down(lsum, o, 64);
        lcnt += __shfl_down(lcnt, o, 64);
    }
    __shared__ float rs[4];
    __shared__ unsigned int rc[4];
    if (!lane) { rs[w] = lsum; rc[w] = lcnt; }
    __syncthreads();
    if (t == 0) {
        double tot = (double)rs[0] + rs[1] + rs[2] + rs[3];
        unsigned int ct = rc[0] + rc[1] + rc[2] + rc[3];
        atomicAdd((double*)accf, tot);
        atomicAdd(((unsigned int*)accf) + 2, ct);
    }
}

__global__ void finalize_kernel(const float* __restrict__ accf, float* __restrict__ out) {
    double s = ((const double*)accf)[0];
    unsigned int c = ((const unsigned int*)accf)[2];
    out[0] = (float)(s / (double)c);
}

extern "C" void kernel_launch(void* const* d_in, const int* in_sizes, int n_in,
                              void* d_out, int out_size, void* d_ws, size_t ws_size,
                              hipStream_t stream) {
    const float* x     = (const float*)d_in[0];
    const float* cam   = (const float*)d_in[1];
    const float* Wq    = (const float*)d_in[2];
    const float* bq    = (const float*)d_in[3];
    const float* Wk    = (const float*)d_in[4];
    const float* bk    = (const float*)d_in[5];
    const float* gamma = (const float*)d_in[6];

    uint8_t* ws = (uint8_t*)d_ws;
    size_t off = 0;
    auto alloc = [&](size_t bytes) {
        void* p = ws + off;
        off = (off + bytes + 255) & ~(size_t)255;
        return p;
    };
    uint8_t*  qT8  = (uint8_t*)alloc((size_t)BB * NN * CC);
    uint8_t*  kT8  = (uint8_t*)alloc((size_t)BB * NN * CC);
    uint8_t*  xT8  = (uint8_t*)alloc((size_t)BB * NN * CC);
    uint8_t*  x8   = (uint8_t*)alloc((size_t)BB * CC * NN);
    uint8_t*  att  = (uint8_t*)alloc((size_t)BB * NN * NN);
    ushort_t* S    = (ushort_t*)alloc((size_t)BB * NN * NN * 2);
    uint8_t*  Wq8  = (uint8_t*)alloc((size_t)CC * CC);
    uint8_t*  Wk8  = (uint8_t*)alloc((size_t)CC * CC);
    float*    qn2  = (float*)alloc((size_t)BB * NN * 4);
    float*    kn2  = (float*)alloc((size_t)BB * NN * 4);
    float*    acc  = (float*)alloc(16);

    hipLaunchKernelGGL(init_kernel, dim3((BB * NN + 255) / 256), dim3(256), 0, stream,
                       qn2, kn2, acc);
    hipLaunchKernelGGL(conv_w, dim3(2 * CC * CC / 4 / 256), dim3(256), 0, stream,
                       Wq, Wk, Wq8, Wk8);
    hipLaunchKernelGGL(conv_x, dim3(NN / 32, CC / 32, BB), dim3(256), 0, stream,
                       x, x8, xT8);
    hipLaunchKernelGGL(gemm_proj, dim3(CC / 128, NN / 128, BB * 2), dim3(256), 0, stream,
                       xT8, Wq8, Wk8, bq, bk, qT8, kT8, qn2, kn2);
    hipLaunchKernelGGL(gemm_energy, dim3(NN / 128, NN / 128, BB), dim3(256), 0, stream,
                       qT8, kT8, S);
    hipLaunchKernelGGL(softmax_kernel, dim3(NN, BB), dim3(256), 0, stream,
                       S, att, qn2, kn2, cam);
    hipLaunchKernelGGL(gemm_out_loss, dim3(NN / 128, CC / 128, BB), dim3(256), 0, stream,
                       x8, att, x, gamma, acc);
    hipLaunchKernelGGL(finalize_kernel, dim3(1), dim3(1), 0, stream, acc, (float*)d_out);
}

// Round 5
// 497.091 us; speedup vs baseline: 1.3717x; 1.3097x over previous
//
#include <hip/hip_runtime.h>
#include <cstdint>
#include <cstddef>

#define BB 4
#define CC 2048
#define HH 48
#define WW 48
#define NN 2304       // HH*WW
#define CAMS 384

typedef unsigned short ushort_t;
typedef float f32x4 __attribute__((ext_vector_type(4)));
typedef long longx2 __attribute__((ext_vector_type(2)));

// ---- bf16 helpers ----
__device__ __forceinline__ ushort_t f2bf(float f) {
    uint32_t u = __builtin_bit_cast(uint32_t, f);
    u += 0x7FFFu + ((u >> 16) & 1u);
    return (ushort_t)(u >> 16);
}
__device__ __forceinline__ float bf2f(ushort_t u) {
    return __builtin_bit_cast(float, (uint32_t)u << 16);
}

// ---- fp8 e4m3 (OCP on gfx950) via HW cvt ----
__device__ __forceinline__ uint32_t pk2fp8(float a, float b) {
    // returns a|b<<8 in low 16 bits
    return (uint32_t)__builtin_amdgcn_cvt_pk_fp8_f32(a, b, 0, false) & 0xFFFFu;
}
__device__ __forceinline__ uint8_t f2fp8(float v) {
    return (uint8_t)(pk2fp8(v, v) & 0xFFu);
}

__device__ __forceinline__ void gld16(const void* g, void* l) {
    __builtin_amdgcn_global_load_lds(
        (const __attribute__((address_space(1))) uint32_t*)g,
        (__attribute__((address_space(3))) uint32_t*)l, 16, 0, 0);
}

// ---- fp8 MFMA mainloop: D[m0..+128][n0..+128] += A[m][k]*B[n][k]
// A: [M][K] fp8 k-fast (K bytes/row), B: [N][K] fp8 k-fast, K % 64 == 0.
// BK = 64 bytes -> LDS rows 64B (4 x 16B chunks), 8KB/buffer, 16KB total.
// Logical chunk c of row r stored at physical c^(r&3).
// Fragment read: ONE ds_read_b128 of logical chunk `quad` per row; its low
// 8B feeds MFMA#0, high 8B feeds MFMA#1 (consistent k-permutation on A and
// B, so the k-sum is exact). Bank pattern = b128 structural floor (each
// bank touched exactly 8x/wave-read) -- the conflict-free m97 class, unlike
// round-4's b64 reads (bank = 16(col&1)+4(col&3) collided 5.66e7 times). --
__device__ __forceinline__ void mfma_mainloop_fp8(
    const uint8_t* __restrict__ A, const uint8_t* __restrict__ B, int K,
    int m0, int n0, uint8_t* sA, uint8_t* sB, f32x4 acc[4][4])
{
    const int t = threadIdx.x;
    const int lane = t & 63;
    const int w = t >> 6;
    const int wm = (w >> 1) * 64;
    const int wn = (w & 1) * 64;
    const int col = lane & 15;
    const int quad = lane >> 4;
    const int lr = lane >> 2;       // row within 16-row staging group
    const int lp = lane & 3;        // physical 16B chunk within 64B row

    for (int k0 = 0; k0 < K; k0 += 64) {
        __syncthreads();
        #pragma unroll
        for (int it = 0; it < 2; it++) {
            const int rg = w * 32 + it * 16;          // wave-uniform row base
            const int r = rg + lr;                    // tile-local row
            const int c = lp ^ (r & 3);               // logical chunk to fetch
            gld16(A + (size_t)(m0 + r) * K + k0 + c * 16, sA + rg * 64);
            gld16(B + (size_t)(n0 + r) * K + k0 + c * 16, sB + rg * 64);
        }
        __syncthreads();
        longx2 af[4], bfr[4];
        #pragma unroll
        for (int i = 0; i < 4; i++) {
            const int m = wm + i * 16 + col;
            af[i] = *(const longx2*)(sA + m * 64 + (quad ^ (m & 3)) * 16);
        }
        #pragma unroll
        for (int j = 0; j < 4; j++) {
            const int n = wn + j * 16 + col;
            bfr[j] = *(const longx2*)(sB + n * 64 + (quad ^ (n & 3)) * 16);
        }
        #pragma unroll
        for (int i = 0; i < 4; i++)
            #pragma unroll
            for (int j = 0; j < 4; j++) {
                acc[i][j] = __builtin_amdgcn_mfma_f32_16x16x32_fp8_fp8(
                    af[i].x, bfr[j].x, acc[i][j], 0, 0, 0);
                acc[i][j] = __builtin_amdgcn_mfma_f32_16x16x32_fp8_fp8(
                    af[i].y, bfr[j].y, acc[i][j], 0, 0, 0);
            }
    }
}

// ---------------- init: zero norm + loss accumulators ----------------
__global__ void init_kernel(float* __restrict__ qn2, float* __restrict__ kn2,
                            float* __restrict__ accf) {
    int t = blockIdx.x * 256 + threadIdx.x;
    if (t < BB * NN) { qn2[t] = 0.f; kn2[t] = 0.f; }
    if (t == 0) { ((double*)accf)[0] = 0.0; ((unsigned int*)accf)[2] = 0u; }
}

// ---------------- W fp32 -> fp8 (layout unchanged, c fast) ----------------
__global__ void conv_w(const float* __restrict__ Wq, const float* __restrict__ Wk,
                       uint8_t* __restrict__ Wq8, uint8_t* __restrict__ Wk8) {
    const int per = CC * CC / 4;
    int idx = blockIdx.x * 256 + threadIdx.x;
    if (idx >= 2 * per) return;
    const float4* src; uint8_t* dst; int i;
    if (idx < per) { src = (const float4*)Wq; dst = Wq8; i = idx; }
    else           { src = (const float4*)Wk; dst = Wk8; i = idx - per; }
    float4 v = src[i];
    *(uint32_t*)(dst + (size_t)i * 4) = pk2fp8(v.x, v.y) | (pk2fp8(v.z, v.w) << 16);
}

// ---------------- x fp32 [b][c][n] -> x8 fp8 same + xT8 fp8 [b][n][c] -----
__global__ void conv_x(const float* __restrict__ x, uint8_t* __restrict__ x8,
                       uint8_t* __restrict__ xT8) {
    __shared__ float tile[32][33];
    const int b = blockIdx.z;
    const int c0 = blockIdx.y * 32, n0 = blockIdx.x * 32;
    const int t = threadIdx.x;
    {
        const int c = t >> 3, n4 = (t & 7) * 4;
        const float4 v = *(const float4*)(x + ((size_t)b * CC + c0 + c) * NN + n0 + n4);
        *(uint32_t*)(x8 + ((size_t)b * CC + c0 + c) * NN + n0 + n4) =
            pk2fp8(v.x, v.y) | (pk2fp8(v.z, v.w) << 16);
        tile[c][n4] = v.x; tile[c][n4 + 1] = v.y;
        tile[c][n4 + 2] = v.z; tile[c][n4 + 3] = v.w;
    }
    __syncthreads();
    {
        const int n = t >> 3, c4 = (t & 7) * 4;
        uint32_t u = pk2fp8(tile[c4][n], tile[c4 + 1][n])
                   | (pk2fp8(tile[c4 + 2][n], tile[c4 + 3][n]) << 16);
        *(uint32_t*)(xT8 + ((size_t)b * NN + n0 + n) * CC + c0 + c4) = u;
    }
}

// ---------------- merged proj (q and k): outT[b][n][o] = sum_c xT[n][c]*W[o][c]+bias
// grid.z = b*2 + which; fused row-norm accumulation from fp32 accs. ----
__global__ __launch_bounds__(256) void gemm_proj(
    const uint8_t* __restrict__ xT8,
    const uint8_t* __restrict__ Wq8, const uint8_t* __restrict__ Wk8,
    const float* __restrict__ bq, const float* __restrict__ bk,
    uint8_t* __restrict__ qT8, uint8_t* __restrict__ kT8,
    float* __restrict__ qn2, float* __restrict__ kn2)
{
    __shared__ __align__(16) uint8_t sA[128 * 64];
    __shared__ __align__(16) uint8_t sB[128 * 64];
    const int z = blockIdx.z;
    const int b = z >> 1, which = z & 1;
    const uint8_t* Wb   = which ? Wk8 : Wq8;
    const float*   bias = which ? bk  : bq;
    uint8_t*       outT = which ? kT8 : qT8;
    float*         nrm  = which ? kn2 : qn2;
    const int m0 = blockIdx.y * 128;   // n
    const int n0 = blockIdx.x * 128;   // o
    f32x4 acc[4][4];
    const f32x4 zz = {0.f, 0.f, 0.f, 0.f};
    #pragma unroll
    for (int i = 0; i < 4; i++)
        #pragma unroll
        for (int j = 0; j < 4; j++) acc[i][j] = zz;
    mfma_mainloop_fp8(xT8 + (size_t)b * NN * CC, Wb, CC, m0, n0, sA, sB, acc);
    const int t = threadIdx.x, lane = t & 63, w = t >> 6;
    const int wm = (w >> 1) * 64, wn = (w & 1) * 64;
    const int col = lane & 15, quad = lane >> 4;
    uint8_t* O = outT + (size_t)b * NN * CC;
    float sq[4][4];
    #pragma unroll
    for (int i = 0; i < 4; i++)
        #pragma unroll
        for (int r = 0; r < 4; r++) sq[i][r] = 0.f;
    #pragma unroll
    for (int j = 0; j < 4; j++) {
        const int gn = n0 + wn + j * 16 + col;     // o
        const float bv = bias[gn];
        #pragma unroll
        for (int i = 0; i < 4; i++) {
            const int gm = m0 + wm + i * 16 + quad * 4;   // n
            #pragma unroll
            for (int r = 0; r < 4; r++) {
                float v = acc[i][j][r] + bv;
                O[(size_t)(gm + r) * CC + gn] = f2fp8(v);
                sq[i][r] += v * v;
            }
        }
    }
    #pragma unroll
    for (int i = 0; i < 4; i++)
        #pragma unroll
        for (int r = 0; r < 4; r++) {
            float s = sq[i][r];
            #pragma unroll
            for (int o = 1; o < 16; o <<= 1) s += __shfl_xor(s, o, 64);
            if (col == 0) {
                const int gm = m0 + wm + i * 16 + quad * 4 + r;
                atomicAdd(&nrm[b * NN + gm], s);
            }
        }
}

// ---------------- energy: S[b][n][m] = sum_o qT[n][o]*kT[m][o] (bf16 out) --
__global__ __launch_bounds__(256) void gemm_energy(
    const uint8_t* __restrict__ qT8, const uint8_t* __restrict__ kT8,
    ushort_t* __restrict__ S)
{
    __shared__ __align__(16) uint8_t sA[128 * 64];
    __shared__ __align__(16) uint8_t sB[128 * 64];
    const int b = blockIdx.z;
    const int m0 = blockIdx.y * 128;   // n
    const int n0 = blockIdx.x * 128;   // m
    f32x4 acc[4][4];
    const f32x4 zz = {0.f, 0.f, 0.f, 0.f};
    #pragma unroll
    for (int i = 0; i < 4; i++)
        #pragma unroll
        for (int j = 0; j < 4; j++) acc[i][j] = zz;
    mfma_mainloop_fp8(qT8 + (size_t)b * NN * CC, kT8 + (size_t)b * NN * CC, CC,
                      m0, n0, sA, sB, acc);
    const int t = threadIdx.x, lane = t & 63, w = t >> 6;
    const int wm = (w >> 1) * 64, wn = (w & 1) * 64;
    const int col = lane & 15, quad = lane >> 4;
    ushort_t* O = S + (size_t)b * NN * NN;
    #pragma unroll
    for (int i = 0; i < 4; i++) {
        const int gm = m0 + wm + i * 16 + quad * 4;
        #pragma unroll
        for (int j = 0; j < 4; j++) {
            const int gn = n0 + wn + j * 16 + col;
            #pragma unroll
            for (int r = 0; r < 4; r++)
                O[(size_t)(gm + r) * NN + gn] = f2bf(acc[i][j][r]);
        }
    }
}

// ---------------- softmax row n over m, scale rsqrt(qn2*kn2), inline mask,
// write att = mask*softmax*256 as fp8 (x256 escapes e4m3 subnormal floor) --
__global__ __launch_bounds__(256) void softmax_kernel(
    const ushort_t* __restrict__ S, uint8_t* __restrict__ att,
    const float* __restrict__ qn2, const float* __restrict__ kn2,
    const float* __restrict__ cam)
{
    const int n = blockIdx.x, b = blockIdx.y;
    const ushort_t* row = S + ((size_t)b * NN + n) * NN;
    uint8_t* orow = att + ((size_t)b * NN + n) * NN;
    const float qinv = rsqrtf(qn2[b * NN + n]);
    // inline bilinear mask for this query row
    const int y = n / WW, xx = n % WW;
    const float ys = (float)(y  * (CAMS - 1)) / (float)(HH - 1);
    const float xs = (float)(xx * (CAMS - 1)) / (float)(WW - 1);
    const int y0 = (int)ys, x0 = (int)xs;
    const int y1 = min(y0 + 1, CAMS - 1), x1 = min(x0 + 1, CAMS - 1);
    const float wy = ys - (float)y0, wx = xs - (float)x0;
    const float* cb = cam + (size_t)b * CAMS * CAMS;
    float c00 = cb[y0 * CAMS + x0]; if (c00 == 255.f) c00 = 0.f;
    float c01 = cb[y0 * CAMS + x1]; if (c01 == 255.f) c01 = 0.f;
    float c10 = cb[y1 * CAMS + x0]; if (c10 == 255.f) c10 = 0.f;
    float c11 = cb[y1 * CAMS + x1]; if (c11 == 255.f) c11 = 0.f;
    const float mv = (1.f - wy) * ((1.f - wx) * c00 + wx * c01)
                   +        wy  * ((1.f - wx) * c10 + wx * c11);
    const float mval = (mv > 0.f) ? 1.f : 0.f;

    const int t = threadIdx.x;
    float v[9];
    float vmax = -3.4e38f;
    #pragma unroll
    for (int i = 0; i < 9; i++) {
        int idx = t + i * 256;
        float s = bf2f(row[idx]) * qinv * rsqrtf(kn2[b * NN + idx]);
        v[i] = s;
        vmax = fmaxf(vmax, s);
    }
    __shared__ float red[8];
    int lane = t & 63, wid = t >> 6;
    #pragma unroll
    for (int o = 32; o; o >>= 1) vmax = fmaxf(vmax, __shfl_down(vmax, o, 64));
    if (!lane) red[wid] = vmax;
    __syncthreads();
    vmax = fmaxf(fmaxf(red[0], red[1]), fmaxf(red[2], red[3]));
    float s = 0.f;
    #pragma unroll
    for (int i = 0; i < 9; i++) { v[i] = __expf(v[i] - vmax); s += v[i]; }
    #pragma unroll
    for (int o = 32; o; o >>= 1) s += __shfl_down(s, o, 64);
    if (!lane) red[4 + wid] = s;
    __syncthreads();
    s = red[4] + red[5] + red[6] + red[7];
    const float scale = mval * 256.f / s;
    #pragma unroll
    for (int i = 0; i < 9; i++) orow[t + i * 256] = f2fp8(v[i] * scale);
}

// ---------------- out: new_x[c][n] = sum_m x8[c][m]*att[n][m]; fused loss --
__global__ __launch_bounds__(256) void gemm_out_loss(
    const uint8_t* __restrict__ x8, const uint8_t* __restrict__ att,
    const float* __restrict__ x, const float* __restrict__ gamma,
    float* __restrict__ accf)
{
    __shared__ __align__(16) uint8_t sA[128 * 64];
    __shared__ __align__(16) uint8_t sB[128 * 64];
    const int b = blockIdx.z;
    const int m0 = blockIdx.y * 128;   // c
    const int n0 = blockIdx.x * 128;   // n
    f32x4 acc[4][4];
    const f32x4 zz = {0.f, 0.f, 0.f, 0.f};
    #pragma unroll
    for (int i = 0; i < 4; i++)
        #pragma unroll
        for (int j = 0; j < 4; j++) acc[i][j] = zz;
    mfma_mainloop_fp8(x8 + (size_t)b * CC * NN, att + (size_t)b * NN * NN, NN,
                      m0, n0, sA, sB, acc);
    const int t = threadIdx.x, lane = t & 63, w = t >> 6;
    const int wm = (w >> 1) * 64, wn = (w & 1) * 64;
    const int col = lane & 15, quad = lane >> 4;
    const float g = gamma[0] * (1.f / 256.f);   // undo att x256 pre-scale
    const float* Xb = x + (size_t)b * CC * NN;
    float lsum = 0.f;
    unsigned int lcnt = 0;
    #pragma unroll
    for (int i = 0; i < 4; i++) {
        const int gm = m0 + wm + i * 16 + quad * 4;   // c
        #pragma unroll
        for (int j = 0; j < 4; j++) {
            const int gn = n0 + wn + j * 16 + col;    // n
            #pragma unroll
            for (int r = 0; r < 4; r++) {
                float xv = Xb[(size_t)(gm + r) * NN + gn];
                float d = xv - g * acc[i][j][r];
                float r2 = d * d;
                lsum += r2;
                lcnt += (r2 != 0.f) ? 1u : 0u;
            }
        }
    }
    #pragma unroll
    for (int o = 32; o; o >>= 1) {
        lsum += __shfl_down(lsum, o, 64);
        lcnt += __shfl_down(lcnt, o, 64);
    }
    __shared__ float rs[4];
    __shared__ unsigned int rc[4];
    if (!lane) { rs[w] = lsum; rc[w] = lcnt; }
    __syncthreads();
    if (t == 0) {
        double tot = (double)rs[0] + rs[1] + rs[2] + rs[3];
        unsigned int ct = rc[0] + rc[1] + rc[2] + rc[3];
        atomicAdd((double*)accf, tot);
        atomicAdd(((unsigned int*)accf) + 2, ct);
    }
}

__global__ void finalize_kernel(const float* __restrict__ accf, float* __restrict__ out) {
    double s = ((const double*)accf)[0];
    unsigned int c = ((const unsigned int*)accf)[2];
    out[0] = (float)(s / (double)c);
}

extern "C" void kernel_launch(void* const* d_in, const int* in_sizes, int n_in,
                              void* d_out, int out_size, void* d_ws, size_t ws_size,
                              hipStream_t stream) {
    const float* x     = (const float*)d_in[0];
    const float* cam   = (const float*)d_in[1];
    const float* Wq    = (const float*)d_in[2];
    const float* bq    = (const float*)d_in[3];
    const float* Wk    = (const float*)d_in[4];
    const float* bk    = (const float*)d_in[5];
    const float* gamma = (const float*)d_in[6];

    uint8_t* ws = (uint8_t*)d_ws;
    size_t off = 0;
    auto alloc = [&](size_t bytes) {
        void* p = ws + off;
        off = (off + bytes + 255) & ~(size_t)255;
        return p;
    };
    uint8_t*  qT8  = (uint8_t*)alloc((size_t)BB * NN * CC);
    uint8_t*  kT8  = (uint8_t*)alloc((size_t)BB * NN * CC);
    uint8_t*  xT8  = (uint8_t*)alloc((size_t)BB * NN * CC);
    uint8_t*  x8   = (uint8_t*)alloc((size_t)BB * CC * NN);
    uint8_t*  att  = (uint8_t*)alloc((size_t)BB * NN * NN);
    ushort_t* S    = (ushort_t*)alloc((size_t)BB * NN * NN * 2);
    uint8_t*  Wq8  = (uint8_t*)alloc((size_t)CC * CC);
    uint8_t*  Wk8  = (uint8_t*)alloc((size_t)CC * CC);
    float*    qn2  = (float*)alloc((size_t)BB * NN * 4);
    float*    kn2  = (float*)alloc((size_t)BB * NN * 4);
    float*    acc  = (float*)alloc(16);

    hipLaunchKernelGGL(init_kernel, dim3((BB * NN + 255) / 256), dim3(256), 0, stream,
                       qn2, kn2, acc);
    hipLaunchKernelGGL(conv_w, dim3(2 * CC * CC / 4 / 256), dim3(256), 0, stream,
                       Wq, Wk, Wq8, Wk8);
    hipLaunchKernelGGL(conv_x, dim3(NN / 32, CC / 32, BB), dim3(256), 0, stream,
                       x, x8, xT8);
    hipLaunchKernelGGL(gemm_proj, dim3(CC / 128, NN / 128, BB * 2), dim3(256), 0, stream,
                       xT8, Wq8, Wk8, bq, bk, qT8, kT8, qn2, kn2);
    hipLaunchKernelGGL(gemm_energy, dim3(NN / 128, NN / 128, BB), dim3(256), 0, stream,
                       qT8, kT8, S);
    hipLaunchKernelGGL(softmax_kernel, dim3(NN, BB), dim3(256), 0, stream,
                       S, att, qn2, kn2, cam);
    hipLaunchKernelGGL(gemm_out_loss, dim3(NN / 128, CC / 128, BB), dim3(256), 0, stream,
                       x8, att, x, gamma, acc);
    hipLaunchKernelGGL(finalize_kernel, dim3(1), dim3(1), 0, stream, acc, (float*)d_out);
}

// Round 6
// 431.929 us; speedup vs baseline: 1.5786x; 1.1509x over previous
//
#include <hip/hip_runtime.h>
#include <cstdint>
#include <cstddef>

#define BB 4
#define CC 2048
#define HH 48
#define WW 48
#define NN 2304       // HH*WW
#define CAMS 384

typedef unsigned short ushort_t;
typedef float f32x4 __attribute__((ext_vector_type(4)));
typedef int i32x4 __attribute__((ext_vector_type(4)));
typedef int i32x8 __attribute__((ext_vector_type(8)));

#define SCALE1 0x7F7F7F7F   // e8m0 127 = 2^0 in every byte -> scale 1.0

// ---- bf16 helpers ----
__device__ __forceinline__ ushort_t f2bf(float f) {
    uint32_t u = __builtin_bit_cast(uint32_t, f);
    u += 0x7FFFu + ((u >> 16) & 1u);
    return (ushort_t)(u >> 16);
}
__device__ __forceinline__ float bf2f(ushort_t u) {
    return __builtin_bit_cast(float, (uint32_t)u << 16);
}

// ---- fp8 e4m3 (OCP on gfx950) via HW cvt ----
__device__ __forceinline__ uint32_t pk2fp8(float a, float b) {
    return (uint32_t)__builtin_amdgcn_cvt_pk_fp8_f32(a, b, 0, false) & 0xFFFFu;
}
__device__ __forceinline__ uint8_t f2fp8(float v) {
    return (uint8_t)(pk2fp8(v, v) & 0xFFu);
}

__device__ __forceinline__ void gld16(const void* g, void* l) {
    __builtin_amdgcn_global_load_lds(
        (const __attribute__((address_space(1))) uint32_t*)g,
        (__attribute__((address_space(3))) uint32_t*)l, 16, 0, 0);
}

// ---- MX-scaled fp8 MFMA mainloop (16x16x128 f8f6f4, scales = 1.0):
// D[m0..+128][n0..+128] += A[m][k]*B[n][k]
// A: [M][K] fp8 k-fast, B: [N][K] fp8 k-fast, K % 128 == 0.
// BK = 128 bytes -> LDS rows 128B (8 x 16B chunks), 16KB/buffer, 32KB total.
// Logical chunk c of row r stored at physical c^(r&7).
// Staging: 8 gld16/thread per k0 (same bytes/k as round-5 BK=64).
// Fragments: lane (col,quad) takes k = quad*32..+31 of its row as TWO
// ds_read_b128 (logical chunks 2q, 2q+1); chunk-class = (2q+h)^(m&7) covers
// every bank exactly 8x per wave-read = structural floor. A and B use the
// identical k-mapping so the reduction is exact. 16 MFMA (2x FLOP each) per
// wave per k0, barriers halved vs BK=64. ----
__device__ __forceinline__ void mfma_mainloop_mx(
    const uint8_t* __restrict__ A, const uint8_t* __restrict__ B, int K,
    int m0, int n0, uint8_t* sA, uint8_t* sB, f32x4 acc[4][4])
{
    const int t = threadIdx.x;
    const int lane = t & 63;
    const int w = t >> 6;
    const int wm = (w >> 1) * 64;
    const int wn = (w & 1) * 64;
    const int col = lane & 15;
    const int quad = lane >> 4;
    const int lr = lane >> 3;       // row within 8-row staging group
    const int lp = lane & 7;        // physical 16B chunk within 128B row

    for (int k0 = 0; k0 < K; k0 += 128) {
        __syncthreads();
        #pragma unroll
        for (int it = 0; it < 4; it++) {
            const int rg = w * 32 + it * 8;           // wave-uniform row base
            const int r = rg + lr;                    // tile-local row
            const int c = lp ^ (r & 7);               // logical chunk to fetch
            gld16(A + (size_t)(m0 + r) * K + k0 + c * 16, sA + rg * 128);
            gld16(B + (size_t)(n0 + r) * K + k0 + c * 16, sB + rg * 128);
        }
        __syncthreads();
        i32x8 bfr[4];
        #pragma unroll
        for (int j = 0; j < 4; j++) {
            const int n = wn + j * 16 + col;
            i32x4 lo = *(const i32x4*)(sB + n * 128 + ((2 * quad) ^ (n & 7)) * 16);
            i32x4 hi = *(const i32x4*)(sB + n * 128 + ((2 * quad + 1) ^ (n & 7)) * 16);
            bfr[j] = (i32x8){lo.x, lo.y, lo.z, lo.w, hi.x, hi.y, hi.z, hi.w};
        }
        #pragma unroll
        for (int i = 0; i < 4; i++) {
            const int m = wm + i * 16 + col;
            i32x4 lo = *(const i32x4*)(sA + m * 128 + ((2 * quad) ^ (m & 7)) * 16);
            i32x4 hi = *(const i32x4*)(sA + m * 128 + ((2 * quad + 1) ^ (m & 7)) * 16);
            i32x8 af = (i32x8){lo.x, lo.y, lo.z, lo.w, hi.x, hi.y, hi.z, hi.w};
            #pragma unroll
            for (int j = 0; j < 4; j++)
                acc[i][j] = __builtin_amdgcn_mfma_scale_f32_16x16x128_f8f6f4(
                    af, bfr[j], acc[i][j], 0, 0,      // cbsz=fp8, blgp=fp8
                    0, SCALE1, 0, SCALE1);            // scales = 1.0
        }
    }
}

// ---------------- init: zero norm + loss accumulators ----------------
__global__ void init_kernel(float* __restrict__ qn2, float* __restrict__ kn2,
                            float* __restrict__ accf) {
    int t = blockIdx.x * 256 + threadIdx.x;
    if (t < BB * NN) { qn2[t] = 0.f; kn2[t] = 0.f; }
    if (t == 0) { ((double*)accf)[0] = 0.0; ((unsigned int*)accf)[2] = 0u; }
}

// ---------------- W fp32 -> fp8 (layout unchanged, c fast) ----------------
__global__ void conv_w(const float* __restrict__ Wq, const float* __restrict__ Wk,
                       uint8_t* __restrict__ Wq8, uint8_t* __restrict__ Wk8) {
    const int per = CC * CC / 4;
    int idx = blockIdx.x * 256 + threadIdx.x;
    if (idx >= 2 * per) return;
    const float4* src; uint8_t* dst; int i;
    if (idx < per) { src = (const float4*)Wq; dst = Wq8; i = idx; }
    else           { src = (const float4*)Wk; dst = Wk8; i = idx - per; }
    float4 v = src[i];
    *(uint32_t*)(dst + (size_t)i * 4) = pk2fp8(v.x, v.y) | (pk2fp8(v.z, v.w) << 16);
}

// ---------------- x fp32 [b][c][n] -> x8 fp8 same + xT8 fp8 [b][n][c] -----
__global__ void conv_x(const float* __restrict__ x, uint8_t* __restrict__ x8,
                       uint8_t* __restrict__ xT8) {
    __shared__ float tile[32][33];
    const int b = blockIdx.z;
    const int c0 = blockIdx.y * 32, n0 = blockIdx.x * 32;
    const int t = threadIdx.x;
    {
        const int c = t >> 3, n4 = (t & 7) * 4;
        const float4 v = *(const float4*)(x + ((size_t)b * CC + c0 + c) * NN + n0 + n4);
        *(uint32_t*)(x8 + ((size_t)b * CC + c0 + c) * NN + n0 + n4) =
            pk2fp8(v.x, v.y) | (pk2fp8(v.z, v.w) << 16);
        tile[c][n4] = v.x; tile[c][n4 + 1] = v.y;
        tile[c][n4 + 2] = v.z; tile[c][n4 + 3] = v.w;
    }
    __syncthreads();
    {
        const int n = t >> 3, c4 = (t & 7) * 4;
        uint32_t u = pk2fp8(tile[c4][n], tile[c4 + 1][n])
                   | (pk2fp8(tile[c4 + 2][n], tile[c4 + 3][n]) << 16);
        *(uint32_t*)(xT8 + ((size_t)b * NN + n0 + n) * CC + c0 + c4) = u;
    }
}

// ---------------- merged proj (q and k): outT[b][n][o] = sum_c xT[n][c]*W[o][c]+bias
// grid.z = b*2 + which; fused row-norm accumulation from fp32 accs. ----
__global__ __launch_bounds__(256) void gemm_proj(
    const uint8_t* __restrict__ xT8,
    const uint8_t* __restrict__ Wq8, const uint8_t* __restrict__ Wk8,
    const float* __restrict__ bq, const float* __restrict__ bk,
    uint8_t* __restrict__ qT8, uint8_t* __restrict__ kT8,
    float* __restrict__ qn2, float* __restrict__ kn2)
{
    __shared__ __align__(16) uint8_t sA[128 * 128];
    __shared__ __align__(16) uint8_t sB[128 * 128];
    const int z = blockIdx.z;
    const int b = z >> 1, which = z & 1;
    const uint8_t* Wb   = which ? Wk8 : Wq8;
    const float*   bias = which ? bk  : bq;
    uint8_t*       outT = which ? kT8 : qT8;
    float*         nrm  = which ? kn2 : qn2;
    const int m0 = blockIdx.y * 128;   // n
    const int n0 = blockIdx.x * 128;   // o
    f32x4 acc[4][4];
    const f32x4 zz = {0.f, 0.f, 0.f, 0.f};
    #pragma unroll
    for (int i = 0; i < 4; i++)
        #pragma unroll
        for (int j = 0; j < 4; j++) acc[i][j] = zz;
    mfma_mainloop_mx(xT8 + (size_t)b * NN * CC, Wb, CC, m0, n0, sA, sB, acc);
    const int t = threadIdx.x, lane = t & 63, w = t >> 6;
    const int wm = (w >> 1) * 64, wn = (w & 1) * 64;
    const int col = lane & 15, quad = lane >> 4;
    uint8_t* O = outT + (size_t)b * NN * CC;
    float sq[4][4];
    #pragma unroll
    for (int i = 0; i < 4; i++)
        #pragma unroll
        for (int r = 0; r < 4; r++) sq[i][r] = 0.f;
    #pragma unroll
    for (int j = 0; j < 4; j++) {
        const int gn = n0 + wn + j * 16 + col;     // o
        const float bv = bias[gn];
        #pragma unroll
        for (int i = 0; i < 4; i++) {
            const int gm = m0 + wm + i * 16 + quad * 4;   // n
            #pragma unroll
            for (int r = 0; r < 4; r++) {
                float v = acc[i][j][r] + bv;
                O[(size_t)(gm + r) * CC + gn] = f2fp8(v);
                sq[i][r] += v * v;
            }
        }
    }
    #pragma unroll
    for (int i = 0; i < 4; i++)
        #pragma unroll
        for (int r = 0; r < 4; r++) {
            float s = sq[i][r];
            #pragma unroll
            for (int o = 1; o < 16; o <<= 1) s += __shfl_xor(s, o, 64);
            if (col == 0) {
                const int gm = m0 + wm + i * 16 + quad * 4 + r;
                atomicAdd(&nrm[b * NN + gm], s);
            }
        }
}

// ---------------- energy: S[b][n][m] = sum_o qT[n][o]*kT[m][o] (bf16 out) --
__global__ __launch_bounds__(256) void gemm_energy(
    const uint8_t* __restrict__ qT8, const uint8_t* __restrict__ kT8,
    ushort_t* __restrict__ S)
{
    __shared__ __align__(16) uint8_t sA[128 * 128];
    __shared__ __align__(16) uint8_t sB[128 * 128];
    const int b = blockIdx.z;
    const int m0 = blockIdx.y * 128;   // n
    const int n0 = blockIdx.x * 128;   // m
    f32x4 acc[4][4];
    const f32x4 zz = {0.f, 0.f, 0.f, 0.f};
    #pragma unroll
    for (int i = 0; i < 4; i++)
        #pragma unroll
        for (int j = 0; j < 4; j++) acc[i][j] = zz;
    mfma_mainloop_mx(qT8 + (size_t)b * NN * CC, kT8 + (size_t)b * NN * CC, CC,
                     m0, n0, sA, sB, acc);
    const int t = threadIdx.x, lane = t & 63, w = t >> 6;
    const int wm = (w >> 1) * 64, wn = (w & 1) * 64;
    const int col = lane & 15, quad = lane >> 4;
    ushort_t* O = S + (size_t)b * NN * NN;
    #pragma unroll
    for (int i = 0; i < 4; i++) {
        const int gm = m0 + wm + i * 16 + quad * 4;
        #pragma unroll
        for (int j = 0; j < 4; j++) {
            const int gn = n0 + wn + j * 16 + col;
            #pragma unroll
            for (int r = 0; r < 4; r++)
                O[(size_t)(gm + r) * NN + gn] = f2bf(acc[i][j][r]);
        }
    }
}

// ---------------- softmax row n over m, scale rsqrt(qn2*kn2), inline mask,
// write att = mask*softmax*256 as fp8 (x256 escapes e4m3 subnormal floor) --
__global__ __launch_bounds__(256) void softmax_kernel(
    const ushort_t* __restrict__ S, uint8_t* __restrict__ att,
    const float* __restrict__ qn2, const float* __restrict__ kn2,
    const float* __restrict__ cam)
{
    const int n = blockIdx.x, b = blockIdx.y;
    const ushort_t* row = S + ((size_t)b * NN + n) * NN;
    uint8_t* orow = att + ((size_t)b * NN + n) * NN;
    const float qinv = rsqrtf(qn2[b * NN + n]);
    // inline bilinear mask for this query row
    const int y = n / WW, xx = n % WW;
    const float ys = (float)(y  * (CAMS - 1)) / (float)(HH - 1);
    const float xs = (float)(xx * (CAMS - 1)) / (float)(WW - 1);
    const int y0 = (int)ys, x0 = (int)xs;
    const int y1 = min(y0 + 1, CAMS - 1), x1 = min(x0 + 1, CAMS - 1);
    const float wy = ys - (float)y0, wx = xs - (float)x0;
    const float* cb = cam + (size_t)b * CAMS * CAMS;
    float c00 = cb[y0 * CAMS + x0]; if (c00 == 255.f) c00 = 0.f;
    float c01 = cb[y0 * CAMS + x1]; if (c01 == 255.f) c01 = 0.f;
    float c10 = cb[y1 * CAMS + x0]; if (c10 == 255.f) c10 = 0.f;
    float c11 = cb[y1 * CAMS + x1]; if (c11 == 255.f) c11 = 0.f;
    const float mv = (1.f - wy) * ((1.f - wx) * c00 + wx * c01)
                   +        wy  * ((1.f - wx) * c10 + wx * c11);
    const float mval = (mv > 0.f) ? 1.f : 0.f;

    const int t = threadIdx.x;
    float v[9];
    float vmax = -3.4e38f;
    #pragma unroll
    for (int i = 0; i < 9; i++) {
        int idx = t + i * 256;
        float s = bf2f(row[idx]) * qinv * rsqrtf(kn2[b * NN + idx]);
        v[i] = s;
        vmax = fmaxf(vmax, s);
    }
    __shared__ float red[8];
    int lane = t & 63, wid = t >> 6;
    #pragma unroll
    for (int o = 32; o; o >>= 1) vmax = fmaxf(vmax, __shfl_down(vmax, o, 64));
    if (!lane) red[wid] = vmax;
    __syncthreads();
    vmax = fmaxf(fmaxf(red[0], red[1]), fmaxf(red[2], red[3]));
    float s = 0.f;
    #pragma unroll
    for (int i = 0; i < 9; i++) { v[i] = __expf(v[i] - vmax); s += v[i]; }
    #pragma unroll
    for (int o = 32; o; o >>= 1) s += __shfl_down(s, o, 64);
    if (!lane) red[4 + wid] = s;
    __syncthreads();
    s = red[4] + red[5] + red[6] + red[7];
    const float scale = mval * 256.f / s;
    #pragma unroll
    for (int i = 0; i < 9; i++) orow[t + i * 256] = f2fp8(v[i] * scale);
}

// ---------------- out: new_x[c][n] = sum_m x8[c][m]*att[n][m]; fused loss --
__global__ __launch_bounds__(256) void gemm_out_loss(
    const uint8_t* __restrict__ x8, const uint8_t* __restrict__ att,
    const float* __restrict__ x, const float* __restrict__ gamma,
    float* __restrict__ accf)
{
    __shared__ __align__(16) uint8_t sA[128 * 128];
    __shared__ __align__(16) uint8_t sB[128 * 128];
    const int b = blockIdx.z;
    const int m0 = blockIdx.y * 128;   // c
    const int n0 = blockIdx.x * 128;   // n
    f32x4 acc[4][4];
    const f32x4 zz = {0.f, 0.f, 0.f, 0.f};
    #pragma unroll
    for (int i = 0; i < 4; i++)
        #pragma unroll
        for (int j = 0; j < 4; j++) acc[i][j] = zz;
    mfma_mainloop_mx(x8 + (size_t)b * CC * NN, att + (size_t)b * NN * NN, NN,
                     m0, n0, sA, sB, acc);
    const int t = threadIdx.x, lane = t & 63, w = t >> 6;
    const int wm = (w >> 1) * 64, wn = (w & 1) * 64;
    const int col = lane & 15, quad = lane >> 4;
    const float g = gamma[0] * (1.f / 256.f);   // undo att x256 pre-scale
    const float* Xb = x + (size_t)b * CC * NN;
    float lsum = 0.f;
    unsigned int lcnt = 0;
    #pragma unroll
    for (int i = 0; i < 4; i++) {
        const int gm = m0 + wm + i * 16 + quad * 4;   // c
        #pragma unroll
        for (int j = 0; j < 4; j++) {
            const int gn = n0 + wn + j * 16 + col;    // n
            #pragma unroll
            for (int r = 0; r < 4; r++) {
                float xv = Xb[(size_t)(gm + r) * NN + gn];
                float d = xv - g * acc[i][j][r];
                float r2 = d * d;
                lsum += r2;
                lcnt += (r2 != 0.f) ? 1u : 0u;
            }
        }
    }
    #pragma unroll
    for (int o = 32; o; o >>= 1) {
        lsum += __shfl_down(lsum, o, 64);
        lcnt += __shfl_down(lcnt, o, 64);
    }
    __shared__ float rs[4];
    __shared__ unsigned int rc[4];
    if (!lane) { rs[w] = lsum; rc[w] = lcnt; }
    __syncthreads();
    if (t == 0) {
        double tot = (double)rs[0] + rs[1] + rs[2] + rs[3];
        unsigned int ct = rc[0] + rc[1] + rc[2] + rc[3];
        atomicAdd((double*)accf, tot);
        atomicAdd(((unsigned int*)accf) + 2, ct);
    }
}

__global__ void finalize_kernel(const float* __restrict__ accf, float* __restrict__ out) {
    double s = ((const double*)accf)[0];
    unsigned int c = ((const unsigned int*)accf)[2];
    out[0] = (float)(s / (double)c);
}

extern "C" void kernel_launch(void* const* d_in, const int* in_sizes, int n_in,
                              void* d_out, int out_size, void* d_ws, size_t ws_size,
                              hipStream_t stream) {
    const float* x     = (const float*)d_in[0];
    const float* cam   = (const float*)d_in[1];
    const float* Wq    = (const float*)d_in[2];
    const float* bq    = (const float*)d_in[3];
    const float* Wk    = (const float*)d_in[4];
    const float* bk    = (const float*)d_in[5];
    const float* gamma = (const float*)d_in[6];

    uint8_t* ws = (uint8_t*)d_ws;
    size_t off = 0;
    auto alloc = [&](size_t bytes) {
        void* p = ws + off;
        off = (off + bytes + 255) & ~(size_t)255;
        return p;
    };
    uint8_t*  qT8  = (uint8_t*)alloc((size_t)BB * NN * CC);
    uint8_t*  kT8  = (uint8_t*)alloc((size_t)BB * NN * CC);
    uint8_t*  xT8  = (uint8_t*)alloc((size_t)BB * NN * CC);
    uint8_t*  x8   = (uint8_t*)alloc((size_t)BB * CC * NN);
    uint8_t*  att  = (uint8_t*)alloc((size_t)BB * NN * NN);
    ushort_t* S    = (ushort_t*)alloc((size_t)BB * NN * NN * 2);
    uint8_t*  Wq8  = (uint8_t*)alloc((size_t)CC * CC);
    uint8_t*  Wk8  = (uint8_t*)alloc((size_t)CC * CC);
    float*    qn2  = (float*)alloc((size_t)BB * NN * 4);
    float*    kn2  = (float*)alloc((size_t)BB * NN * 4);
    float*    acc  = (float*)alloc(16);

    hipLaunchKernelGGL(init_kernel, dim3((BB * NN + 255) / 256), dim3(256), 0, stream,
                       qn2, kn2, acc);
    hipLaunchKernelGGL(conv_w, dim3(2 * CC * CC / 4 / 256), dim3(256), 0, stream,
                       Wq, Wk, Wq8, Wk8);
    hipLaunchKernelGGL(conv_x, dim3(NN / 32, CC / 32, BB), dim3(256), 0, stream,
                       x, x8, xT8);
    hipLaunchKernelGGL(gemm_proj, dim3(CC / 128, NN / 128, BB * 2), dim3(256), 0, stream,
                       xT8, Wq8, Wk8, bq, bk, qT8, kT8, qn2, kn2);
    hipLaunchKernelGGL(gemm_energy, dim3(NN / 128, NN / 128, BB), dim3(256), 0, stream,
                       qT8, kT8, S);
    hipLaunchKernelGGL(softmax_kernel, dim3(NN, BB), dim3(256), 0, stream,
                       S, att, qn2, kn2, cam);
    hipLaunchKernelGGL(gemm_out_loss, dim3(NN / 128, CC / 128, BB), dim3(256), 0, stream,
                       x8, att, x, gamma, acc);
    hipLaunchKernelGGL(finalize_kernel, dim3(1), dim3(1), 0, stream, acc, (float*)d_out);
}